// Round 2
// baseline (395.102 us; speedup 1.0000x reference)
//
#include <hip/hip_runtime.h>

typedef __attribute__((ext_vector_type(8))) short bf16x8;
typedef __attribute__((ext_vector_type(4))) float f32x4;
typedef __attribute__((ext_vector_type(4))) int i32x4;

#define N_NODES 8192
#define D_IN    256
#define D_OUT   128

__device__ __forceinline__ unsigned short bf16_rne(float f) {
  unsigned int u = __float_as_uint(f);
  u += 0x7fffu + ((u >> 16) & 1u);
  return (unsigned short)(u >> 16);
}
__device__ __forceinline__ float bf16_to_f(unsigned short s) {
  return __uint_as_float(((unsigned int)s) << 16);
}

// ---------------- k0a: split x (fp32) -> x_hi, x_lo (bf16) ----------------
__global__ __launch_bounds__(256) void k_split_x(const float* __restrict__ x,
                                                 unsigned short* __restrict__ xhi,
                                                 unsigned short* __restrict__ xlo) {
  int idx = (blockIdx.x * 256 + threadIdx.x) * 8;
  float4 v0 = *(const float4*)(x + idx);
  float4 v1 = *(const float4*)(x + idx + 4);
  float v[8] = {v0.x, v0.y, v0.z, v0.w, v1.x, v1.y, v1.z, v1.w};
  unsigned int hw[4], lw[4];
#pragma unroll
  for (int p = 0; p < 4; ++p) {
    unsigned short h0 = bf16_rne(v[2 * p]);
    unsigned short h1 = bf16_rne(v[2 * p + 1]);
    unsigned short l0 = bf16_rne(v[2 * p] - bf16_to_f(h0));
    unsigned short l1 = bf16_rne(v[2 * p + 1] - bf16_to_f(h1));
    hw[p] = (unsigned int)h0 | ((unsigned int)h1 << 16);
    lw[p] = (unsigned int)l0 | ((unsigned int)l1 << 16);
  }
  *(uint4*)(xhi + idx) = make_uint4(hw[0], hw[1], hw[2], hw[3]);
  *(uint4*)(xlo + idx) = make_uint4(lw[0], lw[1], lw[2], lw[3]);
}

// ------------- k0b: split + transpose W -> W_hiT, W_loT [128][256] -------------
__global__ __launch_bounds__(256) void k_split_w(const float* __restrict__ W,
                                                 unsigned short* __restrict__ whiT,
                                                 unsigned short* __restrict__ wloT) {
  int c = blockIdx.x;
  int k = threadIdx.x;
  float v = W[k * D_OUT + c];
  unsigned short h = bf16_rne(v);
  unsigned short l = bf16_rne(v - bf16_to_f(h));
  whiT[c * D_IN + k] = h;
  wloT[c * D_IN + k] = l;
}

// ---------------- k1: h = x @ W  (split-bf16 MFMA, near-fp32) ----------------
__global__ __launch_bounds__(256) void k_h_gemm(const unsigned short* __restrict__ xhi,
                                                const unsigned short* __restrict__ xlo,
                                                const unsigned short* __restrict__ whiT,
                                                const unsigned short* __restrict__ wloT,
                                                float* __restrict__ h) {
  const int t = threadIdx.x, l = t & 63, wv = t >> 6;
  const int i0 = blockIdx.x * 32;
  const int m = wv >> 1, nh = wv & 1;
  const int frow = l & 15, kq = l >> 4;
  const size_t arow = (size_t)(i0 + m * 16 + frow);
  const unsigned short* pah = xhi + arow * D_IN + kq * 8;
  const unsigned short* pal = xlo + arow * D_IN + kq * 8;
  f32x4 acc[4];
#pragma unroll
  for (int nf = 0; nf < 4; ++nf) acc[nf] = (f32x4){0.f, 0.f, 0.f, 0.f};
#pragma unroll
  for (int kk = 0; kk < 8; ++kk) {
    const int k0 = kk * 32;
    bf16x8 ah = *(const bf16x8*)(pah + k0);
    bf16x8 al = *(const bf16x8*)(pal + k0);
#pragma unroll
    for (int nf = 0; nf < 4; ++nf) {
      const int col = nh * 64 + nf * 16 + frow;
      bf16x8 bh = *(const bf16x8*)(whiT + (size_t)col * D_IN + k0 + kq * 8);
      bf16x8 bl = *(const bf16x8*)(wloT + (size_t)col * D_IN + k0 + kq * 8);
      acc[nf] = __builtin_amdgcn_mfma_f32_16x16x32_bf16(ah, bh, acc[nf], 0, 0, 0);
      acc[nf] = __builtin_amdgcn_mfma_f32_16x16x32_bf16(al, bh, acc[nf], 0, 0, 0);
      acc[nf] = __builtin_amdgcn_mfma_f32_16x16x32_bf16(ah, bl, acc[nf], 0, 0, 0);
    }
  }
#pragma unroll
  for (int nf = 0; nf < 4; ++nf) {
#pragma unroll
    for (int r = 0; r < 4; ++r) {
      const int row = i0 + m * 16 + kq * 4 + r;
      h[(size_t)row * D_OUT + nh * 64 + nf * 16 + frow] = acc[nf][r];
    }
  }
}

// ------- k2a: transpose h -> hT_hi, hT_lo [128][8192] bf16 (hi/lo split) -------
__global__ __launch_bounds__(256) void k_transpose_h(const float* __restrict__ h,
                                                     unsigned short* __restrict__ hThi,
                                                     unsigned short* __restrict__ hTlo) {
  const int t = threadIdx.x;
  const int r0 = blockIdx.x * 64;
  const int c = t >> 1, half = t & 1;
  unsigned int hw[16], lw[16];
#pragma unroll
  for (int p = 0; p < 16; ++p) {
    float v0 = h[(size_t)(r0 + half * 32 + 2 * p) * D_OUT + c];
    float v1 = h[(size_t)(r0 + half * 32 + 2 * p + 1) * D_OUT + c];
    unsigned short h0 = bf16_rne(v0), h1 = bf16_rne(v1);
    unsigned short l0 = bf16_rne(v0 - bf16_to_f(h0));
    unsigned short l1 = bf16_rne(v1 - bf16_to_f(h1));
    hw[p] = (unsigned int)h0 | ((unsigned int)h1 << 16);
    lw[p] = (unsigned int)l0 | ((unsigned int)l1 << 16);
  }
  const size_t off = (size_t)c * N_NODES + r0 + half * 32;
  uint4* ph = (uint4*)(hThi + off);
  uint4* pl = (uint4*)(hTlo + off);
#pragma unroll
  for (int p = 0; p < 4; ++p) {
    ph[p] = make_uint4(hw[4 * p], hw[4 * p + 1], hw[4 * p + 2], hw[4 * p + 3]);
    pl[p] = make_uint4(lw[4 * p], lw[4 * p + 1], lw[4 * p + 2], lw[4 * p + 3]);
  }
}

// ---------------- k2b: src = h@a_src, dst = h@a_dst (fp32) ----------------
__global__ __launch_bounds__(256) void k_src_dst(const float* __restrict__ h,
                                                 const float* __restrict__ a_src,
                                                 const float* __restrict__ a_dst,
                                                 float* __restrict__ srcv,
                                                 float* __restrict__ dstv) {
  const int row = blockIdx.x * 256 + threadIdx.x;
  const float4* hr = (const float4*)(h + (size_t)row * D_OUT);
  float s = 0.f, d = 0.f;
#pragma unroll
  for (int p = 0; p < 32; ++p) {
    float4 hv = hr[p];
    float4 as = ((const float4*)a_src)[p];
    float4 ad = ((const float4*)a_dst)[p];
    s += hv.x * as.x + hv.y * as.y + hv.z * as.z + hv.w * as.w;
    d += hv.x * ad.x + hv.y * ad.y + hv.z * ad.z + hv.w * ad.w;
  }
  srcv[row] = s;
  dstv[row] = d;
}

// ---------------- k3: fused masked-softmax aggregation (barrier-free loop) ----------------
// grid 256 blocks (32 rows), 1024 threads = 16 waves.
// wave wv: m = wv>>3 (16-row frag), cg = (wv>>2)&1 (64-col group, 4 frags),
//          js = wv&3 (j-interleave: j0 = J + js*64). No LDS, no barriers in loop.
// Lane (fr=l&15, kq=l>>4) computes A-frag w[m*16+fr][j0+ks*32+kq*8+e] in registers
// (exact mfma_f32_16x16x32_bf16 A layout, ref-checked in round 1).
__global__ __launch_bounds__(1024) void k_gat(const int* __restrict__ adj,
                                              const float* __restrict__ srcv,
                                              const float* __restrict__ dstv,
                                              const unsigned short* __restrict__ hThi,
                                              const unsigned short* __restrict__ hTlo,
                                              float* __restrict__ out) {
  __shared__ float part[12][1024];  // js=1..3 partial accs: [(js-1)*4 + m*2 + cg][cf*256+(kq*4+r)*16+fr]
  __shared__ float rsl[4][32];      // per-js rowsums

  const int t = threadIdx.x;
  const int l = t & 63, wv = t >> 6;
  const int i0 = blockIdx.x * 32;
  const int m = wv >> 3;
  const int cg = (wv >> 2) & 1;
  const int js = wv & 3;
  const int fr = l & 15, kq = l >> 4;
  const int row = i0 + m * 16 + fr;

  const float src_i = srcv[row];
  const int* adjrow = adj + (size_t)row * N_NODES;
  const unsigned short* bh0 = hThi + (size_t)(cg * 64 + fr) * N_NODES;
  const unsigned short* bl0 = hTlo + (size_t)(cg * 64 + fr) * N_NODES;

  f32x4 acc[4];
#pragma unroll
  for (int cf = 0; cf < 4; ++cf) acc[cf] = (f32x4){0.f, 0.f, 0.f, 0.f};
  float rs = 0.f;

  for (int J = 0; J < N_NODES; J += 256) {
    const int j0 = J + js * 64;
#pragma unroll
    for (int ks = 0; ks < 2; ++ks) {
      const int jb = j0 + ks * 32 + kq * 8;
      i32x4 a0 = __builtin_nontemporal_load((const i32x4*)(adjrow + jb));
      i32x4 a1 = __builtin_nontemporal_load((const i32x4*)(adjrow + jb) + 1);
      f32x4 d0 = *(const f32x4*)(dstv + jb);
      f32x4 d1 = *(const f32x4*)(dstv + jb + 4);
      float w[8];
#pragma unroll
      for (int e = 0; e < 4; ++e) {
        float e0 = src_i + d0[e]; e0 = fmaxf(e0, 0.2f * e0);
        float e1 = src_i + d1[e]; e1 = fmaxf(e1, 0.2f * e1);
        w[e]     = (a0[e] > 0) ? __expf(e0) : 0.f;
        w[4 + e] = (a1[e] > 0) ? __expf(e1) : 0.f;
      }
      if (cg == 0)
        rs += ((w[0] + w[1]) + (w[2] + w[3])) + ((w[4] + w[5]) + (w[6] + w[7]));
      union { bf16x8 v; unsigned int u[4]; } af;
#pragma unroll
      for (int p = 0; p < 4; ++p)
        af.u[p] = (unsigned int)bf16_rne(w[2 * p]) | ((unsigned int)bf16_rne(w[2 * p + 1]) << 16);
#pragma unroll
      for (int cf = 0; cf < 4; ++cf) {
        bf16x8 bh = *(const bf16x8*)(bh0 + (size_t)cf * 16 * N_NODES + jb);
        bf16x8 bl = *(const bf16x8*)(bl0 + (size_t)cf * 16 * N_NODES + jb);
        acc[cf] = __builtin_amdgcn_mfma_f32_16x16x32_bf16(af.v, bh, acc[cf], 0, 0, 0);
        acc[cf] = __builtin_amdgcn_mfma_f32_16x16x32_bf16(af.v, bl, acc[cf], 0, 0, 0);
      }
    }
  }

  // rowsum: sum over kq lanes (bits 4,5 of lane id)
  rs += __shfl_xor(rs, 16);
  rs += __shfl_xor(rs, 32);
  if (cg == 0 && kq == 0) rsl[js][m * 16 + fr] = rs;

  if (js != 0) {
    float* p = &part[(js - 1) * 4 + m * 2 + cg][0];
#pragma unroll
    for (int cf = 0; cf < 4; ++cf)
#pragma unroll
      for (int r = 0; r < 4; ++r)
        p[cf * 256 + (kq * 4 + r) * 16 + fr] = acc[cf][r];
  }
  __syncthreads();

  if (js == 0) {
    const int base = m * 2 + cg;
#pragma unroll
    for (int cf = 0; cf < 4; ++cf) {
#pragma unroll
      for (int r = 0; r < 4; ++r) {
        const int orow = m * 16 + kq * 4 + r;
        const int idx = cf * 256 + (kq * 4 + r) * 16 + fr;
        float v = acc[cf][r] + part[base][idx] + part[4 + base][idx] + part[8 + base][idx];
        float rsum = (rsl[0][orow] + rsl[1][orow]) + (rsl[2][orow] + rsl[3][orow]);
        out[(size_t)(i0 + orow) * D_OUT + cg * 64 + cf * 16 + fr] = v / rsum;
      }
    }
  }
}

extern "C" void kernel_launch(void* const* d_in, const int* in_sizes, int n_in,
                              void* d_out, int out_size, void* d_ws, size_t ws_size,
                              hipStream_t stream) {
  const float* x     = (const float*)d_in[0];
  const int*   adj   = (const int*)d_in[1];
  const float* W     = (const float*)d_in[2];
  const float* a_src = (const float*)d_in[3];
  const float* a_dst = (const float*)d_in[4];
  float* out = (float*)d_out;

  char* ws = (char*)d_ws;
  unsigned short* xhi  = (unsigned short*)(ws);                              // 4 MB
  unsigned short* xlo  = (unsigned short*)(ws + (4 << 20));                  // 4 MB
  unsigned short* whiT = (unsigned short*)(ws + (8 << 20));                  // 64 KB
  unsigned short* wloT = (unsigned short*)(ws + (8 << 20) + (64 << 10));     // 64 KB
  float*          h    = (float*)(ws + (8 << 20) + (128 << 10));             // 4 MB
  unsigned short* hThi = (unsigned short*)(ws + (12 << 20) + (128 << 10));   // 2 MB
  unsigned short* hTlo = (unsigned short*)(ws + (14 << 20) + (128 << 10));   // 2 MB
  float*          srcv = (float*)(ws + (16 << 20) + (128 << 10));            // 32 KB
  float*          dstv = (float*)(ws + (16 << 20) + (160 << 10));            // 32 KB

  k_split_x<<<dim3(1024), dim3(256), 0, stream>>>(x, xhi, xlo);
  k_split_w<<<dim3(128), dim3(256), 0, stream>>>(W, whiT, wloT);
  k_h_gemm<<<dim3(256), dim3(256), 0, stream>>>(xhi, xlo, whiT, wloT, h);
  k_transpose_h<<<dim3(128), dim3(256), 0, stream>>>(h, hThi, hTlo);
  k_src_dst<<<dim3(32), dim3(256), 0, stream>>>(h, a_src, a_dst, srcv, dstv);
  k_gat<<<dim3(256), dim3(1024), 0, stream>>>(adj, srcv, dstv, hThi, hTlo, out);
}

// Round 3
// 268.664 us; speedup vs baseline: 1.4706x; 1.4706x over previous
//
#include <hip/hip_runtime.h>

typedef __attribute__((ext_vector_type(8))) short bf16x8;
typedef __attribute__((ext_vector_type(4))) float f32x4;
typedef __attribute__((ext_vector_type(16))) float f32x16;
typedef __attribute__((ext_vector_type(4))) int i32x4;

#define N_NODES 8192
#define D_IN    256
#define D_OUT   128
#define LOG2E   1.44269504088896f

__device__ __forceinline__ unsigned short bf16_rne(float f) {
  unsigned int u = __float_as_uint(f);
  u += 0x7fffu + ((u >> 16) & 1u);
  return (unsigned short)(u >> 16);
}
__device__ __forceinline__ float bf16_to_f(unsigned short s) {
  return __uint_as_float(((unsigned int)s) << 16);
}

// ---------------- k0a: split x (fp32) -> x_hi, x_lo (bf16) ----------------
__global__ __launch_bounds__(256) void k_split_x(const float* __restrict__ x,
                                                 unsigned short* __restrict__ xhi,
                                                 unsigned short* __restrict__ xlo) {
  int idx = (blockIdx.x * 256 + threadIdx.x) * 8;
  float4 v0 = *(const float4*)(x + idx);
  float4 v1 = *(const float4*)(x + idx + 4);
  float v[8] = {v0.x, v0.y, v0.z, v0.w, v1.x, v1.y, v1.z, v1.w};
  unsigned int hw[4], lw[4];
#pragma unroll
  for (int p = 0; p < 4; ++p) {
    unsigned short h0 = bf16_rne(v[2 * p]);
    unsigned short h1 = bf16_rne(v[2 * p + 1]);
    unsigned short l0 = bf16_rne(v[2 * p] - bf16_to_f(h0));
    unsigned short l1 = bf16_rne(v[2 * p + 1] - bf16_to_f(h1));
    hw[p] = (unsigned int)h0 | ((unsigned int)h1 << 16);
    lw[p] = (unsigned int)l0 | ((unsigned int)l1 << 16);
  }
  *(uint4*)(xhi + idx) = make_uint4(hw[0], hw[1], hw[2], hw[3]);
  *(uint4*)(xlo + idx) = make_uint4(lw[0], lw[1], lw[2], lw[3]);
}

// ------------- k0b: split + transpose W -> W_hiT, W_loT [128][256] -------------
__global__ __launch_bounds__(256) void k_split_w(const float* __restrict__ W,
                                                 unsigned short* __restrict__ whiT,
                                                 unsigned short* __restrict__ wloT) {
  int c = blockIdx.x;
  int k = threadIdx.x;
  float v = W[k * D_OUT + c];
  unsigned short h = bf16_rne(v);
  unsigned short l = bf16_rne(v - bf16_to_f(h));
  whiT[c * D_IN + k] = h;
  wloT[c * D_IN + k] = l;
}

// ---- k1: h = x @ W (split-bf16 MFMA) + fused src/dst dots + B-panel pack ----
// grid 256 blocks (32 rows each), 256 threads = 4 waves.
// Panels: for mfma_f32_32x32x16_bf16 B-frags. Fragment (kstep kg, coltile ct):
//   element (lane l, e) = bf16(h[kg*16 + (l>>5)*8 + e][ct*32 + (l&31)])
//   stored at panel[((kg*4 + ct)*64 + l)*8 + e]  (ushort), so a wave load at
//   base + l*16B is fully coalesced.
__global__ __launch_bounds__(256) void k_h_gemm(const unsigned short* __restrict__ xhi,
                                                const unsigned short* __restrict__ xlo,
                                                const unsigned short* __restrict__ whiT,
                                                const unsigned short* __restrict__ wloT,
                                                const float* __restrict__ a_src,
                                                const float* __restrict__ a_dst,
                                                float* __restrict__ srcv,
                                                float* __restrict__ dstv,
                                                unsigned short* __restrict__ phi,
                                                unsigned short* __restrict__ plo) {
  __shared__ float h_s[32][128];
  const int t = threadIdx.x, l = t & 63, wv = t >> 6;
  const int i0 = blockIdx.x * 32;
  const int m = wv >> 1, nh = wv & 1;
  const int frow = l & 15, kq = l >> 4;
  const size_t arow = (size_t)(i0 + m * 16 + frow);
  const unsigned short* pah = xhi + arow * D_IN + kq * 8;
  const unsigned short* pal = xlo + arow * D_IN + kq * 8;
  f32x4 acc[4];
#pragma unroll
  for (int nf = 0; nf < 4; ++nf) acc[nf] = (f32x4){0.f, 0.f, 0.f, 0.f};
#pragma unroll
  for (int kk = 0; kk < 8; ++kk) {
    const int k0 = kk * 32;
    bf16x8 ah = *(const bf16x8*)(pah + k0);
    bf16x8 al = *(const bf16x8*)(pal + k0);
#pragma unroll
    for (int nf = 0; nf < 4; ++nf) {
      const int col = nh * 64 + nf * 16 + frow;
      bf16x8 bh = *(const bf16x8*)(whiT + (size_t)col * D_IN + k0 + kq * 8);
      bf16x8 bl = *(const bf16x8*)(wloT + (size_t)col * D_IN + k0 + kq * 8);
      acc[nf] = __builtin_amdgcn_mfma_f32_16x16x32_bf16(ah, bh, acc[nf], 0, 0, 0);
      acc[nf] = __builtin_amdgcn_mfma_f32_16x16x32_bf16(al, bh, acc[nf], 0, 0, 0);
      acc[nf] = __builtin_amdgcn_mfma_f32_16x16x32_bf16(ah, bl, acc[nf], 0, 0, 0);
    }
  }
  // stage tile to LDS (C layout: row = m*16+kq*4+r, col = nh*64+nf*16+frow)
#pragma unroll
  for (int nf = 0; nf < 4; ++nf)
#pragma unroll
    for (int r = 0; r < 4; ++r)
      h_s[m * 16 + kq * 4 + r][nh * 64 + nf * 16 + frow] = acc[nf][r];
  __syncthreads();

  // src/dst dots (scaled by log2e so k_gat can use exp2 directly)
  if (t < 32) {
    float s = 0.f, d = 0.f;
#pragma unroll
    for (int c = 0; c < D_OUT; ++c) {
      float v = h_s[t][c];
      s += v * a_src[c];
      d += v * a_dst[c];
    }
    srcv[i0 + t] = s * LOG2E;
    dstv[i0 + t] = d * LOG2E;
  }

  // panel pack: thread t -> (b = t>>7, ct = (t>>5)&3, lw = t&31), both lane-halves
  {
    const int b = t >> 7, ct = (t >> 5) & 3, lw = t & 31;
    const size_t kg = (size_t)(i0 / 16 + b);
#pragma unroll
    for (int half = 0; half < 2; ++half) {
      const int lane = lw + 32 * half;
      unsigned int hw[4], lwd[4];
#pragma unroll
      for (int p = 0; p < 4; ++p) {
        float v0 = h_s[b * 16 + half * 8 + 2 * p][ct * 32 + lw];
        float v1 = h_s[b * 16 + half * 8 + 2 * p + 1][ct * 32 + lw];
        unsigned short h0 = bf16_rne(v0), h1 = bf16_rne(v1);
        unsigned short l0 = bf16_rne(v0 - bf16_to_f(h0));
        unsigned short l1 = bf16_rne(v1 - bf16_to_f(h1));
        hw[p] = (unsigned int)h0 | ((unsigned int)h1 << 16);
        lwd[p] = (unsigned int)l0 | ((unsigned int)l1 << 16);
      }
      const size_t off = ((kg * 4 + ct) * 64 + lane) * 8;
      *(uint4*)(phi + off) = make_uint4(hw[0], hw[1], hw[2], hw[3]);
      *(uint4*)(plo + off) = make_uint4(lwd[0], lwd[1], lwd[2], lwd[3]);
    }
  }
}

// ---------------- k3: fused masked-softmax aggregation ----------------
// grid 256 blocks (32 rows), 1024 threads = 16 waves: ch = wv>>3 (coltile pair),
// js = wv&7 (j-slice). mfma_f32_32x32x16_bf16:
//   A (w): lane l -> A[row = l&31][k = (l>>5)*8 + e]  (computed in registers)
//   B: coalesced frag loads from panels
//   C: row = (reg&3) + 8*(reg>>2) + 4*(l>>5), col = l&31
// No barriers in the main loop; 2-stage manual prefetch of adj + B frags.
__global__ __launch_bounds__(1024) void k_gat(const int* __restrict__ adj,
                                              const float* __restrict__ srcv,
                                              const float* __restrict__ dstv,
                                              const unsigned short* __restrict__ phi,
                                              const unsigned short* __restrict__ plo,
                                              float* __restrict__ out) {
  __shared__ float4 dstv_s[2048];   // 32 KB (log2e-scaled dstv)
  __shared__ float parts[14][2048]; // 112 KB partial accumulators
  __shared__ float rsl[8][32];      // per-js rowsums

  const int t = threadIdx.x, l = t & 63, wv = t >> 6;
  const int ch = wv >> 3, js = wv & 7;
  const int i0 = blockIdx.x * 32;
  const int r32 = l & 31, kh = l >> 5;

  // stage dstv -> LDS
  dstv_s[t * 2] = ((const float4*)dstv)[t * 2];
  dstv_s[t * 2 + 1] = ((const float4*)dstv)[t * 2 + 1];
  __syncthreads();

  const float s2 = srcv[i0 + r32];
  const int* adjp = adj + (size_t)(i0 + r32) * N_NODES + kh * 8;
  const int ct0 = ch * 2;

  f32x16 acc0, acc1;
#pragma unroll
  for (int q = 0; q < 16; ++q) { acc0[q] = 0.f; acc1[q] = 0.f; }
  float rs = 0.f;

  // prologue: loads for it = 0
  int jb = js * 16;
  int kst = js;
  i32x4 a0 = __builtin_nontemporal_load((const i32x4*)(adjp + jb));
  i32x4 a1 = __builtin_nontemporal_load((const i32x4*)(adjp + jb) + 1);
  bf16x8 b0h = *(const bf16x8*)(phi + ((size_t)(kst * 4 + ct0) * 64 + l) * 8);
  bf16x8 b0l = *(const bf16x8*)(plo + ((size_t)(kst * 4 + ct0) * 64 + l) * 8);
  bf16x8 b1h = *(const bf16x8*)(phi + ((size_t)(kst * 4 + ct0 + 1) * 64 + l) * 8);
  bf16x8 b1l = *(const bf16x8*)(plo + ((size_t)(kst * 4 + ct0 + 1) * 64 + l) * 8);

  for (int it = 0; it < 64; ++it) {
    // issue next iteration's loads first (overlap with this iteration's compute)
    const int itn = (it < 63) ? it + 1 : 63;
    const int jbn = itn * 128 + js * 16;
    const int kstn = itn * 8 + js;
    i32x4 na0 = __builtin_nontemporal_load((const i32x4*)(adjp + jbn));
    i32x4 na1 = __builtin_nontemporal_load((const i32x4*)(adjp + jbn) + 1);
    bf16x8 nb0h = *(const bf16x8*)(phi + ((size_t)(kstn * 4 + ct0) * 64 + l) * 8);
    bf16x8 nb0l = *(const bf16x8*)(plo + ((size_t)(kstn * 4 + ct0) * 64 + l) * 8);
    bf16x8 nb1h = *(const bf16x8*)(phi + ((size_t)(kstn * 4 + ct0 + 1) * 64 + l) * 8);
    bf16x8 nb1l = *(const bf16x8*)(plo + ((size_t)(kstn * 4 + ct0 + 1) * 64 + l) * 8);

    // w A-fragment (fp32 math, bf16 pack); dstv from LDS (broadcast)
    const int didx = (jb + kh * 8) >> 2;
    float4 d0 = dstv_s[didx];
    float4 d1 = dstv_s[didx + 1];
    float w[8];
#pragma unroll
    for (int e = 0; e < 4; ++e) {
      float e0 = s2 + ((const float*)&d0)[e];
      float e1 = s2 + ((const float*)&d1)[e];
      e0 = fmaxf(e0, 0.2f * e0);
      e1 = fmaxf(e1, 0.2f * e1);
      w[e]     = (a0[e] > 0) ? exp2f(e0) : 0.f;
      w[4 + e] = (a1[e] > 0) ? exp2f(e1) : 0.f;
    }
    if (ch == 0)
      rs += ((w[0] + w[1]) + (w[2] + w[3])) + ((w[4] + w[5]) + (w[6] + w[7]));
    union { bf16x8 v; unsigned int u[4]; } af;
#pragma unroll
    for (int p = 0; p < 4; ++p)
      af.u[p] = (unsigned int)bf16_rne(w[2 * p]) | ((unsigned int)bf16_rne(w[2 * p + 1]) << 16);

    acc0 = __builtin_amdgcn_mfma_f32_32x32x16_bf16(af.v, b0h, acc0, 0, 0, 0);
    acc0 = __builtin_amdgcn_mfma_f32_32x32x16_bf16(af.v, b0l, acc0, 0, 0, 0);
    acc1 = __builtin_amdgcn_mfma_f32_32x32x16_bf16(af.v, b1h, acc1, 0, 0, 0);
    acc1 = __builtin_amdgcn_mfma_f32_32x32x16_bf16(af.v, b1l, acc1, 0, 0, 0);

    // rotate pipeline
    a0 = na0; a1 = na1;
    b0h = nb0h; b0l = nb0l; b1h = nb1h; b1l = nb1l;
    jb = jbn;
  }

  // rowsum: combine kh halves, stash per-js
  rs += __shfl_xor(rs, 32);
  if (ch == 0 && kh == 0) rsl[js][r32] = rs;

  // partials to LDS (js != 0), single barrier, js == 0 reduces
  if (js != 0) {
    float* p = &parts[ch * 7 + js - 1][0];
#pragma unroll
    for (int reg = 0; reg < 16; ++reg) {
      p[reg * 64 + l] = acc0[reg];
      p[1024 + reg * 64 + l] = acc1[reg];
    }
  }
  __syncthreads();

  if (js == 0) {
#pragma unroll
    for (int cc = 0; cc < 2; ++cc) {
#pragma unroll
      for (int reg = 0; reg < 16; ++reg) {
        float v = cc ? acc1[reg] : acc0[reg];
#pragma unroll
        for (int q = 0; q < 7; ++q) v += parts[ch * 7 + q][cc * 1024 + reg * 64 + l];
        const int row = (reg & 3) + 8 * (reg >> 2) + 4 * kh;
        float rsum = ((rsl[0][row] + rsl[1][row]) + (rsl[2][row] + rsl[3][row])) +
                     ((rsl[4][row] + rsl[5][row]) + (rsl[6][row] + rsl[7][row]));
        out[(size_t)(i0 + row) * D_OUT + ch * 64 + cc * 32 + r32] = v / rsum;
      }
    }
  }
}

extern "C" void kernel_launch(void* const* d_in, const int* in_sizes, int n_in,
                              void* d_out, int out_size, void* d_ws, size_t ws_size,
                              hipStream_t stream) {
  const float* x     = (const float*)d_in[0];
  const int*   adj   = (const int*)d_in[1];
  const float* W     = (const float*)d_in[2];
  const float* a_src = (const float*)d_in[3];
  const float* a_dst = (const float*)d_in[4];
  float* out = (float*)d_out;

  char* ws = (char*)d_ws;
  unsigned short* xhi  = (unsigned short*)(ws);                               // 4 MB
  unsigned short* xlo  = (unsigned short*)(ws + (4 << 20));                   // 4 MB
  unsigned short* whiT = (unsigned short*)(ws + (8 << 20));                   // 64 KB
  unsigned short* wloT = (unsigned short*)(ws + (8 << 20) + (64 << 10));      // 64 KB
  unsigned short* phi  = (unsigned short*)(ws + (8 << 20) + (128 << 10));     // 2 MB
  unsigned short* plo  = (unsigned short*)(ws + (10 << 20) + (128 << 10));    // 2 MB
  float*          srcv = (float*)(ws + (12 << 20) + (128 << 10));             // 32 KB
  float*          dstv = (float*)(ws + (12 << 20) + (160 << 10));             // 32 KB

  k_split_x<<<dim3(1024), dim3(256), 0, stream>>>(x, xhi, xlo);
  k_split_w<<<dim3(128), dim3(256), 0, stream>>>(W, whiT, wloT);
  k_h_gemm<<<dim3(256), dim3(256), 0, stream>>>(xhi, xlo, whiT, wloT,
                                                a_src, a_dst, srcv, dstv, phi, plo);
  k_gat<<<dim3(256), dim3(1024), 0, stream>>>(adj, srcv, dstv, phi, plo, out);
}

// Round 4
// 243.481 us; speedup vs baseline: 1.6227x; 1.1034x over previous
//
#include <hip/hip_runtime.h>

typedef __attribute__((ext_vector_type(8))) short bf16x8;
typedef __attribute__((ext_vector_type(4))) float f32x4;
typedef __attribute__((ext_vector_type(16))) float f32x16;
typedef __attribute__((ext_vector_type(4))) int i32x4;

#define N_NODES 8192
#define D_IN    256
#define D_OUT   128
#define LOG2E   1.44269504088896f

__device__ __forceinline__ unsigned short bf16_rne(float f) {
  unsigned int u = __float_as_uint(f);
  u += 0x7fffu + ((u >> 16) & 1u);
  return (unsigned short)(u >> 16);
}
__device__ __forceinline__ float bf16_to_f(unsigned short s) {
  return __uint_as_float(((unsigned int)s) << 16);
}

// ---------------- k0a: split x (fp32) -> x_hi, x_lo (bf16) ----------------
__global__ __launch_bounds__(256) void k_split_x(const float* __restrict__ x,
                                                 unsigned short* __restrict__ xhi,
                                                 unsigned short* __restrict__ xlo) {
  int idx = (blockIdx.x * 256 + threadIdx.x) * 8;
  float4 v0 = *(const float4*)(x + idx);
  float4 v1 = *(const float4*)(x + idx + 4);
  float v[8] = {v0.x, v0.y, v0.z, v0.w, v1.x, v1.y, v1.z, v1.w};
  unsigned int hw[4], lw[4];
#pragma unroll
  for (int p = 0; p < 4; ++p) {
    unsigned short h0 = bf16_rne(v[2 * p]);
    unsigned short h1 = bf16_rne(v[2 * p + 1]);
    unsigned short l0 = bf16_rne(v[2 * p] - bf16_to_f(h0));
    unsigned short l1 = bf16_rne(v[2 * p + 1] - bf16_to_f(h1));
    hw[p] = (unsigned int)h0 | ((unsigned int)h1 << 16);
    lw[p] = (unsigned int)l0 | ((unsigned int)l1 << 16);
  }
  *(uint4*)(xhi + idx) = make_uint4(hw[0], hw[1], hw[2], hw[3]);
  *(uint4*)(xlo + idx) = make_uint4(lw[0], lw[1], lw[2], lw[3]);
}

// ------------- k0b: split + transpose W -> W_hiT, W_loT [128][256] -------------
__global__ __launch_bounds__(256) void k_split_w(const float* __restrict__ W,
                                                 unsigned short* __restrict__ whiT,
                                                 unsigned short* __restrict__ wloT) {
  int c = blockIdx.x;
  int k = threadIdx.x;
  float v = W[k * D_OUT + c];
  unsigned short h = bf16_rne(v);
  unsigned short l = bf16_rne(v - bf16_to_f(h));
  whiT[c * D_IN + k] = h;
  wloT[c * D_IN + k] = l;
}

// ---- k1: h = x @ W (split-bf16 MFMA) + fused src/dst dots + B-panel pack ----
// Panels for mfma_f32_32x32x16_bf16 B-frags: fragment (kstep kg, coltile ct):
//   element (lane l, e) = bf16(h[kg*16 + (l>>5)*8 + e][ct*32 + (l&31)])
//   at panel[((kg*4 + ct)*64 + l)*8 + e] -> wave load at base + l*16B coalesced.
__global__ __launch_bounds__(256) void k_h_gemm(const unsigned short* __restrict__ xhi,
                                                const unsigned short* __restrict__ xlo,
                                                const unsigned short* __restrict__ whiT,
                                                const unsigned short* __restrict__ wloT,
                                                const float* __restrict__ a_src,
                                                const float* __restrict__ a_dst,
                                                float* __restrict__ srcv,
                                                float* __restrict__ dstv,
                                                unsigned short* __restrict__ phi,
                                                unsigned short* __restrict__ plo) {
  __shared__ float h_s[32][128];
  const int t = threadIdx.x, l = t & 63, wv = t >> 6;
  const int i0 = blockIdx.x * 32;
  const int m = wv >> 1, nh = wv & 1;
  const int frow = l & 15, kq = l >> 4;
  const size_t arow = (size_t)(i0 + m * 16 + frow);
  const unsigned short* pah = xhi + arow * D_IN + kq * 8;
  const unsigned short* pal = xlo + arow * D_IN + kq * 8;
  f32x4 acc[4];
#pragma unroll
  for (int nf = 0; nf < 4; ++nf) acc[nf] = (f32x4){0.f, 0.f, 0.f, 0.f};
#pragma unroll
  for (int kk = 0; kk < 8; ++kk) {
    const int k0 = kk * 32;
    bf16x8 ah = *(const bf16x8*)(pah + k0);
    bf16x8 al = *(const bf16x8*)(pal + k0);
#pragma unroll
    for (int nf = 0; nf < 4; ++nf) {
      const int col = nh * 64 + nf * 16 + frow;
      bf16x8 bh = *(const bf16x8*)(whiT + (size_t)col * D_IN + k0 + kq * 8);
      bf16x8 bl = *(const bf16x8*)(wloT + (size_t)col * D_IN + k0 + kq * 8);
      acc[nf] = __builtin_amdgcn_mfma_f32_16x16x32_bf16(ah, bh, acc[nf], 0, 0, 0);
      acc[nf] = __builtin_amdgcn_mfma_f32_16x16x32_bf16(al, bh, acc[nf], 0, 0, 0);
      acc[nf] = __builtin_amdgcn_mfma_f32_16x16x32_bf16(ah, bl, acc[nf], 0, 0, 0);
    }
  }
#pragma unroll
  for (int nf = 0; nf < 4; ++nf)
#pragma unroll
    for (int r = 0; r < 4; ++r)
      h_s[m * 16 + kq * 4 + r][nh * 64 + nf * 16 + frow] = acc[nf][r];
  __syncthreads();

  if (t < 32) {
    float s = 0.f, d = 0.f;
#pragma unroll
    for (int c = 0; c < D_OUT; ++c) {
      float v = h_s[t][c];
      s += v * a_src[c];
      d += v * a_dst[c];
    }
    srcv[i0 + t] = s * LOG2E;
    dstv[i0 + t] = d * LOG2E;
  }

  {
    const int b = t >> 7, ct = (t >> 5) & 3, lw = t & 31;
    const size_t kg = (size_t)(i0 / 16 + b);
#pragma unroll
    for (int half = 0; half < 2; ++half) {
      const int lane = lw + 32 * half;
      unsigned int hw[4], lwd[4];
#pragma unroll
      for (int p = 0; p < 4; ++p) {
        float v0 = h_s[b * 16 + half * 8 + 2 * p][ct * 32 + lw];
        float v1 = h_s[b * 16 + half * 8 + 2 * p + 1][ct * 32 + lw];
        unsigned short h0 = bf16_rne(v0), h1 = bf16_rne(v1);
        unsigned short l0 = bf16_rne(v0 - bf16_to_f(h0));
        unsigned short l1 = bf16_rne(v1 - bf16_to_f(h1));
        hw[p] = (unsigned int)h0 | ((unsigned int)h1 << 16);
        lwd[p] = (unsigned int)l0 | ((unsigned int)l1 << 16);
      }
      const size_t off = ((kg * 4 + ct) * 64 + lane) * 8;
      *(uint4*)(phi + off) = make_uint4(hw[0], hw[1], hw[2], hw[3]);
      *(uint4*)(plo + off) = make_uint4(lwd[0], lwd[1], lwd[2], lwd[3]);
    }
  }
}

// ---------------- k3: fused masked-softmax aggregation (j-split v4) ----------------
// grid 512 = 256 row-tiles x 2 j-halves; 512 threads = 8 waves: ch = wv>>2, js = wv&3.
// Per wave-iter: 32 j (2 k-steps). Lane (r32 = l&31, kh = l>>5) owns row i0+r32 and,
// jointly with its kh-sibling, the FULL 128B adj line [jb, jb+32) ints:
//   kh=0 loads [0,8)+[16,24), kh=1 loads [8,16)+[24,32).
// A-frag (32x32x16): lane -> A[r32][kh*8+e] per 16-j k-step (layout ref-checked r3).
// Partial numerators/rowsums -> ws; k_comb merges the two j-halves.
__global__ __launch_bounds__(512) void k_gat(const int* __restrict__ adj,
                                             const float* __restrict__ srcv,
                                             const float* __restrict__ dstv,
                                             const unsigned short* __restrict__ phi,
                                             const unsigned short* __restrict__ plo,
                                             float* __restrict__ pnum,
                                             float* __restrict__ prsum) {
  __shared__ float dstv_s[4096];   // 16 KB: this block's j-half of dstv
  __shared__ float red[2][2048];   // 16 KB: reusable js-reduction buffer
  __shared__ float rsl[4][32];

  const int t = threadIdx.x, l = t & 63, wv = t >> 6;
  const int ch = wv >> 2, js = wv & 3;
  const int bid = blockIdx.x;
  const int tile = bid & 255, jh = bid >> 8;
  const int i0 = tile * 32;
  const int r32 = l & 31, kh = l >> 5;

  {
    const float4* s4 = (const float4*)(dstv + jh * 4096);
    float4* d4 = (float4*)dstv_s;
    d4[t] = s4[t];
    d4[t + 512] = s4[t + 512];
  }
  __syncthreads();

  const float s2 = srcv[i0 + r32];
  const int* adjp = adj + (size_t)(i0 + r32) * N_NODES + jh * 4096 + kh * 8;
  const int ct0 = ch * 2;

  f32x16 acc0, acc1;
#pragma unroll
  for (int q = 0; q < 16; ++q) { acc0[q] = 0.f; acc1[q] = 0.f; }
  float rs = 0.f;

  // prologue: adj for it = 0
  int jb = js * 32;
  i32x4 a0 = __builtin_nontemporal_load((const i32x4*)(adjp + jb));
  i32x4 a1 = __builtin_nontemporal_load((const i32x4*)(adjp + jb + 4));
  i32x4 a2 = __builtin_nontemporal_load((const i32x4*)(adjp + jb + 16));
  i32x4 a3 = __builtin_nontemporal_load((const i32x4*)(adjp + jb + 20));

  for (int it = 0; it < 32; ++it) {
    // next iteration's adj (HBM latency hidden under this iteration)
    const int itn = (it < 31) ? it + 1 : 31;
    const int jbn = itn * 128 + js * 32;
    i32x4 n0 = __builtin_nontemporal_load((const i32x4*)(adjp + jbn));
    i32x4 n1 = __builtin_nontemporal_load((const i32x4*)(adjp + jbn + 4));
    i32x4 n2 = __builtin_nontemporal_load((const i32x4*)(adjp + jbn + 16));
    i32x4 n3 = __builtin_nontemporal_load((const i32x4*)(adjp + jbn + 20));

    // this iteration's B fragments (L2/L3-resident panels, coalesced 1KB/instr)
    const int kst = jh * 256 + it * 8 + js * 2;
    const size_t f00 = ((size_t)(kst * 4 + ct0) * 64 + l) * 8;
    const size_t f01 = ((size_t)(kst * 4 + ct0 + 1) * 64 + l) * 8;
    const size_t f10 = ((size_t)((kst + 1) * 4 + ct0) * 64 + l) * 8;
    const size_t f11 = ((size_t)((kst + 1) * 4 + ct0 + 1) * 64 + l) * 8;
    bf16x8 bh00 = *(const bf16x8*)(phi + f00);
    bf16x8 bl00 = *(const bf16x8*)(plo + f00);
    bf16x8 bh01 = *(const bf16x8*)(phi + f01);
    bf16x8 bl01 = *(const bf16x8*)(plo + f01);
    bf16x8 bh10 = *(const bf16x8*)(phi + f10);
    bf16x8 bl10 = *(const bf16x8*)(plo + f10);
    bf16x8 bh11 = *(const bf16x8*)(phi + f11);
    bf16x8 bl11 = *(const bf16x8*)(plo + f11);

    // w fragments (fp32 math, bf16 pack); dstv broadcast from LDS
    const int jl = it * 128 + js * 32 + kh * 8;
    f32x4 dv0 = *(const f32x4*)&dstv_s[jl];
    f32x4 dv1 = *(const f32x4*)&dstv_s[jl + 4];
    f32x4 dv2 = *(const f32x4*)&dstv_s[jl + 16];
    f32x4 dv3 = *(const f32x4*)&dstv_s[jl + 20];
    float w0[8], w1[8];
#pragma unroll
    for (int e = 0; e < 4; ++e) {
      float e0 = s2 + dv0[e]; e0 = fmaxf(e0, 0.2f * e0);
      float e1 = s2 + dv1[e]; e1 = fmaxf(e1, 0.2f * e1);
      float e2 = s2 + dv2[e]; e2 = fmaxf(e2, 0.2f * e2);
      float e3 = s2 + dv3[e]; e3 = fmaxf(e3, 0.2f * e3);
      w0[e]     = (a0[e] > 0) ? exp2f(e0) : 0.f;
      w0[4 + e] = (a1[e] > 0) ? exp2f(e1) : 0.f;
      w1[e]     = (a2[e] > 0) ? exp2f(e2) : 0.f;
      w1[4 + e] = (a3[e] > 0) ? exp2f(e3) : 0.f;
    }
    if (ch == 0)
      rs += (((w0[0] + w0[1]) + (w0[2] + w0[3])) + ((w0[4] + w0[5]) + (w0[6] + w0[7]))) +
            (((w1[0] + w1[1]) + (w1[2] + w1[3])) + ((w1[4] + w1[5]) + (w1[6] + w1[7])));
    union { bf16x8 v; unsigned int u[4]; } af0, af1;
#pragma unroll
    for (int p = 0; p < 4; ++p) {
      af0.u[p] = (unsigned int)bf16_rne(w0[2 * p]) | ((unsigned int)bf16_rne(w0[2 * p + 1]) << 16);
      af1.u[p] = (unsigned int)bf16_rne(w1[2 * p]) | ((unsigned int)bf16_rne(w1[2 * p + 1]) << 16);
    }

    acc0 = __builtin_amdgcn_mfma_f32_32x32x16_bf16(af0.v, bh00, acc0, 0, 0, 0);
    acc0 = __builtin_amdgcn_mfma_f32_32x32x16_bf16(af0.v, bl00, acc0, 0, 0, 0);
    acc1 = __builtin_amdgcn_mfma_f32_32x32x16_bf16(af0.v, bh01, acc1, 0, 0, 0);
    acc1 = __builtin_amdgcn_mfma_f32_32x32x16_bf16(af0.v, bl01, acc1, 0, 0, 0);
    acc0 = __builtin_amdgcn_mfma_f32_32x32x16_bf16(af1.v, bh10, acc0, 0, 0, 0);
    acc0 = __builtin_amdgcn_mfma_f32_32x32x16_bf16(af1.v, bl10, acc0, 0, 0, 0);
    acc1 = __builtin_amdgcn_mfma_f32_32x32x16_bf16(af1.v, bh11, acc1, 0, 0, 0);
    acc1 = __builtin_amdgcn_mfma_f32_32x32x16_bf16(af1.v, bl11, acc1, 0, 0, 0);

    a0 = n0; a1 = n1; a2 = n2; a3 = n3;
  }

  // rowsum across kh halves; stash per js
  rs += __shfl_xor(rs, 32);
  if (ch == 0 && kh == 0) rsl[js][r32] = rs;

  // js-reduction of numerators, 3 rounds through a 16 KB buffer
#pragma unroll
  for (int q = 1; q < 4; ++q) {
    if (js == q) {
#pragma unroll
      for (int reg = 0; reg < 16; ++reg) {
        red[ch][reg * 64 + l] = acc0[reg];
        red[ch][1024 + reg * 64 + l] = acc1[reg];
      }
    }
    __syncthreads();
    if (js == 0) {
#pragma unroll
      for (int reg = 0; reg < 16; ++reg) {
        acc0[reg] += red[ch][reg * 64 + l];
        acc1[reg] += red[ch][1024 + reg * 64 + l];
      }
    }
    __syncthreads();
  }

  if (js == 0) {
    float* pn = pnum + (size_t)bid * 4096;
#pragma unroll
    for (int reg = 0; reg < 16; ++reg) {
      const int row = (reg & 3) + 8 * (reg >> 2) + 4 * kh;
      pn[row * 128 + ch * 64 + r32] = acc0[reg];
      pn[row * 128 + ch * 64 + 32 + r32] = acc1[reg];
    }
    if (ch == 0 && kh == 0)
      prsum[bid * 32 + r32] = (rsl[0][r32] + rsl[1][r32]) + (rsl[2][r32] + rsl[3][r32]);
  }
}

// ---------------- k4: merge j-halves, divide by rowsum ----------------
__global__ __launch_bounds__(1024) void k_comb(const float* __restrict__ pnum,
                                               const float* __restrict__ prsum,
                                               float* __restrict__ out) {
  const int tile = blockIdx.x, t = threadIdx.x;
  const float4 a = ((const float4*)(pnum + (size_t)tile * 4096))[t];
  const float4 b = ((const float4*)(pnum + (size_t)(256 + tile) * 4096))[t];
  const int row = t >> 5;
  const float r = prsum[tile * 32 + row] + prsum[(256 + tile) * 32 + row];
  float4 o;
  o.x = (a.x + b.x) / r;
  o.y = (a.y + b.y) / r;
  o.z = (a.z + b.z) / r;
  o.w = (a.w + b.w) / r;
  ((float4*)(out + (size_t)tile * 4096))[t] = o;
}

extern "C" void kernel_launch(void* const* d_in, const int* in_sizes, int n_in,
                              void* d_out, int out_size, void* d_ws, size_t ws_size,
                              hipStream_t stream) {
  const float* x     = (const float*)d_in[0];
  const int*   adj   = (const int*)d_in[1];
  const float* W     = (const float*)d_in[2];
  const float* a_src = (const float*)d_in[3];
  const float* a_dst = (const float*)d_in[4];
  float* out = (float*)d_out;

  char* ws = (char*)d_ws;
  unsigned short* xhi  = (unsigned short*)(ws);                               // 4 MB (dead after k_h_gemm)
  unsigned short* xlo  = (unsigned short*)(ws + (4 << 20));                   // 4 MB (dead after k_h_gemm)
  unsigned short* whiT = (unsigned short*)(ws + (8 << 20));                   // 64 KB
  unsigned short* wloT = (unsigned short*)(ws + (8 << 20) + (64 << 10));      // 64 KB
  unsigned short* phi  = (unsigned short*)(ws + (8 << 20) + (128 << 10));     // 2 MB
  unsigned short* plo  = (unsigned short*)(ws + (10 << 20) + (128 << 10));    // 2 MB
  float*          srcv = (float*)(ws + (12 << 20) + (128 << 10));             // 32 KB
  float*          dstv = (float*)(ws + (12 << 20) + (160 << 10));             // 32 KB
  float*          pnum = (float*)(ws);                                        // 8 MB, aliases xhi/xlo
  float*          prsum= (float*)(ws + (12 << 20) + (192 << 10));             // 64 KB

  k_split_x<<<dim3(1024), dim3(256), 0, stream>>>(x, xhi, xlo);
  k_split_w<<<dim3(128), dim3(256), 0, stream>>>(W, whiT, wloT);
  k_h_gemm<<<dim3(256), dim3(256), 0, stream>>>(xhi, xlo, whiT, wloT,
                                                a_src, a_dst, srcv, dstv, phi, plo);
  k_gat<<<dim3(512), dim3(512), 0, stream>>>(adj, srcv, dstv, phi, plo, pnum, prsum);
  k_comb<<<dim3(256), dim3(1024), 0, stream>>>(pnum, prsum, out);
}